// Round 6
// baseline (117.093 us; speedup 1.0000x reference)
//
#include <hip/hip_runtime.h>
#include <hip/hip_bf16.h>

// DCRNN single-step, algebraically reduced (proven rounds 2-5):
//   xm = x * mask
//   Z  = sigmoid(xm @ WzE + bz),  WzE = w_z[0,0][:256] + w_z[1,0][:256]
//   Ht = tanh   (xm @ WhE + bh)
//   h  = elu((1 - Z) * Ht)         // H=0 -> Z*H drops; R/w_r/b_r dead; edges dead
//   out = h @ w_lin.T + b_lin      // f32 output
//
// Split-bf16 MFMA (v = hi + lo; hi*hi + lo*hi + hi*lo, f32 acc) — math bit-identical
// to rounds 3-5. Round-6: latency attack — (1) nontemporal x/mask loads + out
// stores (protect L2-resident weights from stream eviction), (2) software-pipelined
// B-fragment prefetch (counted vmcnt, never drains), (3) h packed (hi,lo) in one
// u32 LDS word (word-granular transport, less epilogue VALU).

typedef __attribute__((ext_vector_type(8))) short bf16x8;   // 8 bf16 = 4 VGPR
typedef __attribute__((ext_vector_type(4))) float f32x4;

constexpr int N_ROWS = 50000;
constexpr int CIN  = 256;
constexpr int COUT = 64;
constexpr int BM   = 32;

__device__ inline unsigned short f2bf(float f) {          // RNE f32 -> bf16 bits
    union { float f; unsigned u; } v; v.f = f;
    unsigned r = v.u + 0x7fffu + ((v.u >> 16) & 1u);
    return (unsigned short)(r >> 16);
}
__device__ inline float bf2f(unsigned short b) {
    union { unsigned u; float f; } v; v.u = ((unsigned)b) << 16;
    return v.f;
}
__device__ inline f32x4 mfma16(bf16x8 a, bf16x8 b, f32x4 c) {
    return __builtin_amdgcn_mfma_f32_16x16x32_bf16(a, b, c, 0, 0, 0);
}

// ---------------- weight prep: B-fragment-ordered hi/lo bf16 (proven) ----------------
// Fragment f holds, for lane l, 8 bf16: B[k = kb*32 + (l>>4)*8 + j][n = nf*16 + (l&15)]
// gate frags f = ((g*2+p)*16 + nf)*8 + kb   g:0=Z,1=H  p:0=hi,1=lo  nf<16 kb<8  -> [0,512)
// out  frags f = 512 + (p*4 + nf)*8 + kb    nf<4                               -> [512,576)
__global__ __launch_bounds__(256) void prep_frags(
    const float* __restrict__ wz, const float* __restrict__ wh,
    const float* __restrict__ wlin, unsigned short* __restrict__ ws)
{
    int t = blockIdx.x * 256 + threadIdx.x;
    int frag = t >> 6, lane = t & 63;
    if (frag >= 576) return;
    int g16 = lane & 15, kg = lane >> 4;
    unsigned short vals[8];
    if (frag < 512) {
        int kb = frag & 7, nf = (frag >> 3) & 15, p = (frag >> 7) & 1, g = frag >> 8;
        const float* wsrc = g ? wh : wz;
        int n = nf * 16 + g16;
        #pragma unroll
        for (int j = 0; j < 8; ++j) {
            int k = kb * 32 + kg * 8 + j;
            float v = wsrc[k * 256 + n] + wsrc[131072 + k * 256 + n];  // tap0 + tap1
            unsigned short hi = f2bf(v);
            vals[j] = (p == 0) ? hi : f2bf(v - bf2f(hi));
        }
    } else {
        int f = frag - 512;
        int kb = f & 7, nf = (f >> 3) & 3, p = f >> 5;
        int n = nf * 16 + g16;                       // output column o
        #pragma unroll
        for (int j = 0; j < 8; ++j) {
            int k = kb * 32 + kg * 8 + j;
            float v = wlin[n * 256 + k];             // B[k][o] = w_lin[o][k]
            unsigned short hi = f2bf(v);
            vals[j] = (p == 0) ? hi : f2bf(v - bf2f(hi));
        }
    }
    unsigned short* dst = ws + (size_t)frag * 512 + lane * 8;
    #pragma unroll
    for (int j = 0; j < 8; ++j) dst[j] = vals[j];
}

__device__ inline bf16x8 ldfrag(const unsigned short* wf, int frag, int lane) {
    return *reinterpret_cast<const bf16x8*>(wf + (size_t)frag * 512 + lane * 8);
}

// ---------------- fused MFMA kernel (BM=32, pipelined) ----------------
__global__ __launch_bounds__(256, 4) void dcrnn_mfma(
    const float* __restrict__ x, const float* __restrict__ mask,
    const unsigned short* __restrict__ wf,
    const float* __restrict__ bz, const float* __restrict__ bh,
    const float* __restrict__ blin, float* __restrict__ out)
{
    __shared__ char smem[32768];               // phase A/B: Ahi|Alo bf16; phase C: h packed u32
    char* AhiB = smem;                         // 16 KB, XOR-swizzled bf16 x_hi (32x256)
    char* AloB = smem + 16384;                 // 16 KB, XOR-swizzled bf16 x_lo
    const int tid = threadIdx.x, lane = tid & 63, wv = tid >> 6;
    const int l16 = lane & 15, lk = lane >> 4;
    const int row0 = blockIdx.x * BM;
    const int nfg0 = wv * 4;

    // ---- issue first B-fragment loads before staging barrier (overlap) ----
    bf16x8 cZh = ldfrag(wf, (nfg0)      * 8, lane);
    bf16x8 cZl = ldfrag(wf, (16 + nfg0) * 8, lane);
    bf16x8 cHh = ldfrag(wf, (32 + nfg0) * 8, lane);
    bf16x8 cHl = ldfrag(wf, (48 + nfg0) * 8, lane);

    // ---- stage xm = x*mask -> hi/lo bf16 in LDS (nontemporal f32x4, swizzled writes) ----
    #pragma unroll
    for (int it = 0; it < 8; ++it) {
        int f = it * 256 + tid;                // float4 slot in 32x256 tile
        int r = f >> 6, c4 = f & 63;
        int row = row0 + r;
        f32x4 xv = (f32x4){0.f, 0.f, 0.f, 0.f}, mv = xv;
        if (row < N_ROWS) {
            xv = __builtin_nontemporal_load(
                reinterpret_cast<const f32x4*>(x + (size_t)row * CIN) + c4);
            mv = __builtin_nontemporal_load(
                reinterpret_cast<const f32x4*>(mask + (size_t)row * CIN) + c4);
        }
        float v0 = xv[0] * mv[0], v1 = xv[1] * mv[1], v2 = xv[2] * mv[2], v3 = xv[3] * mv[3];
        unsigned short h0 = f2bf(v0), h1 = f2bf(v1), h2 = f2bf(v2), h3 = f2bf(v3);
        unsigned short l0 = f2bf(v0 - bf2f(h0)), l1 = f2bf(v1 - bf2f(h1));
        unsigned short l2 = f2bf(v2 - bf2f(h2)), l3 = f2bf(v3 - bf2f(h3));
        int byte = ((r * CIN + c4 * 4) * 2) ^ ((r & 7) << 4);     // T2 swizzle, 16B slots
        *reinterpret_cast<ushort4*>(AhiB + byte) = make_ushort4(h0, h1, h2, h3);
        *reinterpret_cast<ushort4*>(AloB + byte) = make_ushort4(l0, l1, l2, l3);
    }
    __syncthreads();

    // ---- gate GEMMs: wave wv owns cols [wv*64, wv*64+64) of BOTH Z and Ht; 32 rows ----
    f32x4 accZ[2][4], accH[2][4];
    #pragma unroll
    for (int m = 0; m < 2; ++m)
        #pragma unroll
        for (int nf = 0; nf < 4; ++nf) {
            accZ[m][nf] = (f32x4){0.f, 0.f, 0.f, 0.f};
            accH[m][nf] = (f32x4){0.f, 0.f, 0.f, 0.f};
        }

    bf16x8 ah[2], al[2];
    {   // A-frags for kb=0
        int koff = lk * 8;
        #pragma unroll
        for (int m = 0; m < 2; ++m) {
            int row = m * 16 + l16;
            int byte = ((row * CIN + koff) * 2) ^ ((row & 7) << 4);
            ah[m] = *reinterpret_cast<const bf16x8*>(AhiB + byte);
            al[m] = *reinterpret_cast<const bf16x8*>(AloB + byte);
        }
    }

    for (int kb = 0; kb < 8; ++kb) {
        #pragma unroll
        for (int nf = 0; nf < 4; ++nf) {
            // prefetch next (kb,nf) B-frags (depth-1; harmless dummy read at the tail)
            int nnf = (nf + 1) & 3;
            int nkb = kb + (nf == 3 ? 1 : 0);
            int nkbc = nkb > 7 ? 7 : nkb;      // clamp: tail prefetch re-reads kb=7 (unused)
            bf16x8 nZh = ldfrag(wf, (nfg0 + nnf)      * 8 + nkbc, lane);
            bf16x8 nZl = ldfrag(wf, (16 + nfg0 + nnf) * 8 + nkbc, lane);
            bf16x8 nHh = ldfrag(wf, (32 + nfg0 + nnf) * 8 + nkbc, lane);
            bf16x8 nHl = ldfrag(wf, (48 + nfg0 + nnf) * 8 + nkbc, lane);
            // MFMAs on current frags
            #pragma unroll
            for (int m = 0; m < 2; ++m) {
                accZ[m][nf] = mfma16(ah[m], cZh, accZ[m][nf]);
                accZ[m][nf] = mfma16(al[m], cZh, accZ[m][nf]);
                accZ[m][nf] = mfma16(ah[m], cZl, accZ[m][nf]);
                accH[m][nf] = mfma16(ah[m], cHh, accH[m][nf]);
                accH[m][nf] = mfma16(al[m], cHh, accH[m][nf]);
                accH[m][nf] = mfma16(ah[m], cHl, accH[m][nf]);
            }
            if (nf == 3) {                     // A-frags for next kb (clamped at tail)
                int akb = kb < 7 ? kb + 1 : 7;
                int koff = akb * 32 + lk * 8;
                #pragma unroll
                for (int m = 0; m < 2; ++m) {
                    int row = m * 16 + l16;
                    int byte = ((row * CIN + koff) * 2) ^ ((row & 7) << 4);
                    ah[m] = *reinterpret_cast<const bf16x8*>(AhiB + byte);
                    al[m] = *reinterpret_cast<const bf16x8*>(AloB + byte);
                }
            }
            cZh = nZh; cZl = nZl; cHh = nHh; cHl = nHl;
        }
    }
    __syncthreads();   // all waves done reading x tiles before h overwrites smem

    // ---- nonlinearities + GRU blend; h -> LDS as packed (hi<<16)|lo u32 ----
    #pragma unroll
    for (int nf = 0; nf < 4; ++nf) {
        int col = wv * 64 + nf * 16 + l16;
        float bzv = bz[col], bhv = bh[col];
        #pragma unroll
        for (int m = 0; m < 2; ++m) {
            #pragma unroll
            for (int i = 0; i < 4; ++i) {
                float z  = 1.f / (1.f + __expf(-(accZ[m][nf][i] + bzv)));
                float t  = __expf(2.f * (accH[m][nf][i] + bhv));
                float th = (t - 1.f) / (t + 1.f);
                float H  = (1.f - z) * th;
                float h  = (H > 0.f) ? H : (__expf(H) - 1.f);   // elu(alpha=1)
                int row = m * 16 + lk * 4 + i;                  // C/D: row=(lane>>4)*4+reg
                unsigned short hh = f2bf(h);
                unsigned short hl = f2bf(h - bf2f(hh));
                unsigned pk = ((unsigned)hh << 16) | (unsigned)hl;
                int byte = (row * 1024 + col * 4) ^ ((row & 7) << 4);  // u32 row stride 1 KB
                *reinterpret_cast<unsigned*>(smem + byte) = pk;
            }
        }
    }
    __syncthreads();

    // ---- out GEMM: wave wv owns out-cols [wv*16, wv*16+16), all 32 rows; pipelined ----
    f32x4 accO[2];
    #pragma unroll
    for (int m = 0; m < 2; ++m) accO[m] = (f32x4){0.f, 0.f, 0.f, 0.f};

    bf16x8 cbh = ldfrag(wf, 512 + (wv)     * 8, lane);
    bf16x8 cbl = ldfrag(wf, 512 + (4 + wv) * 8, lane);

    for (int kb = 0; kb < 8; ++kb) {
        int nk = kb < 7 ? kb + 1 : 7;
        bf16x8 nbh = ldfrag(wf, 512 + (wv)     * 8 + nk, lane);
        bf16x8 nbl = ldfrag(wf, 512 + (4 + wv) * 8 + nk, lane);
        #pragma unroll
        for (int m = 0; m < 2; ++m) {
            int row = m * 16 + l16;
            int e0  = kb * 32 + lk * 8;
            int b0  = (row * 1024 + e0 * 4)      ^ ((row & 7) << 4);
            int b1  = (row * 1024 + e0 * 4 + 16) ^ ((row & 7) << 4);
            uint4 p0 = *reinterpret_cast<const uint4*>(smem + b0);
            uint4 p1 = *reinterpret_cast<const uint4*>(smem + b1);
            bf16x8 ha, la;
            ha[0] = (short)(p0.x >> 16); la[0] = (short)(p0.x & 0xffffu);
            ha[1] = (short)(p0.y >> 16); la[1] = (short)(p0.y & 0xffffu);
            ha[2] = (short)(p0.z >> 16); la[2] = (short)(p0.z & 0xffffu);
            ha[3] = (short)(p0.w >> 16); la[3] = (short)(p0.w & 0xffffu);
            ha[4] = (short)(p1.x >> 16); la[4] = (short)(p1.x & 0xffffu);
            ha[5] = (short)(p1.y >> 16); la[5] = (short)(p1.y & 0xffffu);
            ha[6] = (short)(p1.z >> 16); la[6] = (short)(p1.z & 0xffffu);
            ha[7] = (short)(p1.w >> 16); la[7] = (short)(p1.w & 0xffffu);
            accO[m] = mfma16(ha, cbh, accO[m]);
            accO[m] = mfma16(la, cbh, accO[m]);
            accO[m] = mfma16(ha, cbl, accO[m]);
        }
        cbh = nbh; cbl = nbl;
    }
    {
        int col = wv * 16 + l16;
        float bo = blin[col];
        #pragma unroll
        for (int m = 0; m < 2; ++m)
            #pragma unroll
            for (int i = 0; i < 4; ++i) {
                int row = row0 + m * 16 + lk * 4 + i;
                if (row < N_ROWS)
                    __builtin_nontemporal_store(accO[m][i] + bo,
                                                &out[(size_t)row * COUT + col]);
            }
    }
}

// ---------------- fallback: round-2 f32 kernel (proven; used only if ws too small) ----------------
__global__ __launch_bounds__(256) void fallback_f32(
    const float* __restrict__ x, const float* __restrict__ mask,
    const float* __restrict__ wzr, const float* __restrict__ whr,
    const float* __restrict__ bz, const float* __restrict__ bh,
    const float* __restrict__ wlinr, const float* __restrict__ blin,
    float* __restrict__ out)
{
    __shared__ float xm[32][CIN];
    const int tid = threadIdx.x;
    const int row0 = blockIdx.x * 32;
    #pragma unroll
    for (int it = 0; it < 8; ++it) {
        int idx = it * 256 + tid;
        int r = idx >> 6, c4 = idx & 63, row = row0 + r;
        float4 v = make_float4(0.f, 0.f, 0.f, 0.f);
        if (row < N_ROWS) {
            float4 a = reinterpret_cast<const float4*>(x    + (size_t)row * CIN)[c4];
            float4 m = reinterpret_cast<const float4*>(mask + (size_t)row * CIN)[c4];
            v = make_float4(a.x * m.x, a.y * m.y, a.z * m.z, a.w * m.w);
        }
        reinterpret_cast<float4*>(&xm[r][0])[c4] = v;
    }
    __syncthreads();
    const int j0 = (tid & 63) * 4, r0 = (tid >> 6) * 8;
    float accz[4][8], acch[4][8];
    #pragma unroll
    for (int c = 0; c < 4; ++c)
        #pragma unroll
        for (int r = 0; r < 8; ++r) { accz[c][r] = 0.f; acch[c][r] = 0.f; }
    for (int k = 0; k < CIN; k += 4) {
        float4 wz4[4], wh4[4];
        #pragma unroll
        for (int kk = 0; kk < 4; ++kk) {
            float4 a0 = *reinterpret_cast<const float4*>(&wzr[(k + kk) * 256 + j0]);
            float4 a1 = *reinterpret_cast<const float4*>(&wzr[131072 + (k + kk) * 256 + j0]);
            wz4[kk] = make_float4(a0.x + a1.x, a0.y + a1.y, a0.z + a1.z, a0.w + a1.w);
            float4 b0 = *reinterpret_cast<const float4*>(&whr[(k + kk) * 256 + j0]);
            float4 b1 = *reinterpret_cast<const float4*>(&whr[131072 + (k + kk) * 256 + j0]);
            wh4[kk] = make_float4(b0.x + b1.x, b0.y + b1.y, b0.z + b1.z, b0.w + b1.w);
        }
        #pragma unroll
        for (int r = 0; r < 8; ++r) {
            float4 xv = *reinterpret_cast<const float4*>(&xm[r0 + r][k]);
            float xk[4] = {xv.x, xv.y, xv.z, xv.w};
            float wzc[4][4] = {{wz4[0].x,wz4[0].y,wz4[0].z,wz4[0].w},{wz4[1].x,wz4[1].y,wz4[1].z,wz4[1].w},
                               {wz4[2].x,wz4[2].y,wz4[2].z,wz4[2].w},{wz4[3].x,wz4[3].y,wz4[3].z,wz4[3].w}};
            float whc[4][4] = {{wh4[0].x,wh4[0].y,wh4[0].z,wh4[0].w},{wh4[1].x,wh4[1].y,wh4[1].z,wh4[1].w},
                               {wh4[2].x,wh4[2].y,wh4[2].z,wh4[2].w},{wh4[3].x,wh4[3].y,wh4[3].z,wh4[3].w}};
            #pragma unroll
            for (int kk = 0; kk < 4; ++kk)
                #pragma unroll
                for (int c = 0; c < 4; ++c) {
                    accz[c][r] = fmaf(xk[kk], wzc[kk][c], accz[c][r]);
                    acch[c][r] = fmaf(xk[kk], whc[kk][c], acch[c][r]);
                }
        }
    }
    float bzj[4], bhj[4];
    #pragma unroll
    for (int c = 0; c < 4; ++c) { bzj[c] = bz[j0 + c]; bhj[c] = bh[j0 + c]; }
    __syncthreads();
    #pragma unroll
    for (int r = 0; r < 8; ++r) {
        float hc[4];
        #pragma unroll
        for (int c = 0; c < 4; ++c) {
            float z  = 1.f / (1.f + expf(-(accz[c][r] + bzj[c])));
            float ht = tanhf(acch[c][r] + bhj[c]);
            float H  = (1.f - z) * ht;
            hc[c] = (H > 0.f) ? H : expm1f(H);
        }
        *reinterpret_cast<float4*>(&xm[r0 + r][j0]) = make_float4(hc[0], hc[1], hc[2], hc[3]);
    }
    __syncthreads();
    const int o = tid & 63;
    float acc[8];
    #pragma unroll
    for (int r = 0; r < 8; ++r) acc[r] = 0.f;
    for (int k = 0; k < CIN; k += 4) {
        float4 wv4 = *reinterpret_cast<const float4*>(&wlinr[o * 256 + k]);
        #pragma unroll
        for (int r = 0; r < 8; ++r) {
            float4 hv = *reinterpret_cast<const float4*>(&xm[r0 + r][k]);
            acc[r] = fmaf(hv.x, wv4.x, acc[r]);
            acc[r] = fmaf(hv.y, wv4.y, acc[r]);
            acc[r] = fmaf(hv.z, wv4.z, acc[r]);
            acc[r] = fmaf(hv.w, wv4.w, acc[r]);
        }
    }
    float bo = blin[o];
    #pragma unroll
    for (int r = 0; r < 8; ++r) {
        int row = row0 + r0 + r;
        if (row < N_ROWS) out[(size_t)row * COUT + o] = acc[r] + bo;
    }
}

extern "C" void kernel_launch(void* const* d_in, const int* in_sizes, int n_in,
                              void* d_out, int out_size, void* d_ws, size_t ws_size,
                              hipStream_t stream)
{
    const float* x    = (const float*)d_in[0];
    // d_in[1] edge_index, d_in[2] edge_weight: unused (K=1 identity term only)
    const float* mask = (const float*)d_in[3];
    const float* wz   = (const float*)d_in[4];
    const float* bz   = (const float*)d_in[5];
    // d_in[6] w_r, d_in[7] b_r: dead (H=0 -> reset gate unused)
    const float* wh   = (const float*)d_in[8];
    const float* bh   = (const float*)d_in[9];
    const float* wlin = (const float*)d_in[10];
    const float* blin = (const float*)d_in[11];
    float* outf = (float*)d_out;

    const size_t ws_need = 576 * 1024;   // 576 frags x 1 KB
    if (ws_size >= ws_need) {
        unsigned short* wsf = (unsigned short*)d_ws;
        prep_frags<<<144, 256, 0, stream>>>(wz, wh, wlin, wsf);
        dcrnn_mfma<<<(N_ROWS + BM - 1) / BM, 256, 0, stream>>>(
            x, mask, wsf, bz, bh, blin, outf);
    } else {
        fallback_f32<<<(N_ROWS + 31) / 32, 256, 0, stream>>>(
            x, mask, wz, wh, bz, bh, wlin, blin, outf);
    }
}

// Round 7
// 64.311 us; speedup vs baseline: 1.8207x; 1.8207x over previous
//
#include <hip/hip_runtime.h>
#include <hip/hip_bf16.h>

// DCRNN single-step, algebraically reduced (proven rounds 2-6):
//   xm = x * mask
//   Z  = sigmoid(xm @ WzE + bz),  WzE = w_z[0,0][:256] + w_z[1,0][:256]
//   Ht = tanh   (xm @ WhE + bh)
//   h  = elu((1 - Z) * Ht)         // H=0 -> Z*H drops; R/w_r/b_r dead; edges dead
//   out = h @ w_lin.T + b_lin      // f32 output
//
// Split-bf16 MFMA: x = xhi + xlo kept (both gate terms); WEIGHT-lo terms dropped
// (error bound ~9e-3 pre-activation, analyzed round 7) -> 2 B-loads + 8 MFMAs per
// gate iter, 1 MFMA per out iter, weight set 288 KB (L2-resident per XCD).
// Round-7: reverted ALL nontemporal (R6 showed nt bypasses L3 -> FETCH +65%).

typedef __attribute__((ext_vector_type(8))) short bf16x8;   // 8 bf16 = 4 VGPR
typedef __attribute__((ext_vector_type(4))) float f32x4;

constexpr int N_ROWS = 50000;
constexpr int CIN  = 256;
constexpr int COUT = 64;
constexpr int BM   = 32;

__device__ inline unsigned short f2bf(float f) {          // RNE f32 -> bf16 bits
    union { float f; unsigned u; } v; v.f = f;
    unsigned r = v.u + 0x7fffu + ((v.u >> 16) & 1u);
    return (unsigned short)(r >> 16);
}
__device__ inline float bf2f(unsigned short b) {
    union { unsigned u; float f; } v; v.u = ((unsigned)b) << 16;
    return v.f;
}
__device__ inline f32x4 mfma16(bf16x8 a, bf16x8 b, f32x4 c) {
    return __builtin_amdgcn_mfma_f32_16x16x32_bf16(a, b, c, 0, 0, 0);
}

// ---------------- weight prep: B-fragment-ordered bf16 (hi only) ----------------
// Fragment f holds, for lane l, 8 bf16: B[k = kb*32 + (l>>4)*8 + j][n = nf*16 + (l&15)]
// gate frags f = (g*16 + nf)*8 + kb   g:0=Z,1=H   nf<16 kb<8   -> [0,256)
// out  frags f = 256 + nf*8 + kb      nf<4                     -> [256,288)
__global__ __launch_bounds__(256) void prep_frags(
    const float* __restrict__ wz, const float* __restrict__ wh,
    const float* __restrict__ wlin, unsigned short* __restrict__ ws)
{
    int t = blockIdx.x * 256 + threadIdx.x;
    int frag = t >> 6, lane = t & 63;
    if (frag >= 288) return;
    int g16 = lane & 15, kg = lane >> 4;
    unsigned short vals[8];
    if (frag < 256) {
        int kb = frag & 7, nf = (frag >> 3) & 15, g = frag >> 7;
        const float* wsrc = g ? wh : wz;
        int n = nf * 16 + g16;
        #pragma unroll
        for (int j = 0; j < 8; ++j) {
            int k = kb * 32 + kg * 8 + j;
            float v = wsrc[k * 256 + n] + wsrc[131072 + k * 256 + n];  // tap0 + tap1
            vals[j] = f2bf(v);
        }
    } else {
        int f = frag - 256;
        int kb = f & 7, nf = f >> 3;
        int n = nf * 16 + g16;                       // output column o
        #pragma unroll
        for (int j = 0; j < 8; ++j) {
            int k = kb * 32 + kg * 8 + j;
            vals[j] = f2bf(wlin[n * 256 + k]);       // B[k][o] = w_lin[o][k]
        }
    }
    unsigned short* dst = ws + (size_t)frag * 512 + lane * 8;
    #pragma unroll
    for (int j = 0; j < 8; ++j) dst[j] = vals[j];
}

__device__ inline bf16x8 ldfrag(const unsigned short* wf, int frag, int lane) {
    return *reinterpret_cast<const bf16x8*>(wf + (size_t)frag * 512 + lane * 8);
}

// ---------------- fused MFMA kernel (BM=32, W-hi only, depth-1 prefetch) ----------------
__global__ __launch_bounds__(256, 3) void dcrnn_mfma(
    const float* __restrict__ x, const float* __restrict__ mask,
    const unsigned short* __restrict__ wf,
    const float* __restrict__ bz, const float* __restrict__ bh,
    const float* __restrict__ blin, float* __restrict__ out)
{
    __shared__ char smem[32768];               // phase A/B: Ahi|Alo bf16; phase C: h (bf16<<16) u32
    char* AhiB = smem;                         // 16 KB, XOR-swizzled bf16 x_hi (32x256)
    char* AloB = smem + 16384;                 // 16 KB, XOR-swizzled bf16 x_lo
    const int tid = threadIdx.x, lane = tid & 63, wv = tid >> 6;
    const int l16 = lane & 15, lk = lane >> 4;
    const int row0 = blockIdx.x * BM;
    const int nfg0 = wv * 4;

    // ---- issue first B-fragment loads before staging (overlap with HBM latency) ----
    bf16x8 cZ = ldfrag(wf, (nfg0)      * 8, lane);
    bf16x8 cH = ldfrag(wf, (16 + nfg0) * 8, lane);

    // ---- stage xm = x*mask -> hi/lo bf16 in LDS (plain f32x4 loads, swizzled writes) ----
    #pragma unroll
    for (int it = 0; it < 8; ++it) {
        int f = it * 256 + tid;                // float4 slot in 32x256 tile
        int r = f >> 6, c4 = f & 63;
        int row = row0 + r;
        float4 xv = make_float4(0.f, 0.f, 0.f, 0.f), mv = xv;
        if (row < N_ROWS) {
            xv = reinterpret_cast<const float4*>(x    + (size_t)row * CIN)[c4];
            mv = reinterpret_cast<const float4*>(mask + (size_t)row * CIN)[c4];
        }
        float v0 = xv.x * mv.x, v1 = xv.y * mv.y, v2 = xv.z * mv.z, v3 = xv.w * mv.w;
        unsigned short h0 = f2bf(v0), h1 = f2bf(v1), h2 = f2bf(v2), h3 = f2bf(v3);
        unsigned short l0 = f2bf(v0 - bf2f(h0)), l1 = f2bf(v1 - bf2f(h1));
        unsigned short l2 = f2bf(v2 - bf2f(h2)), l3 = f2bf(v3 - bf2f(h3));
        int byte = ((r * CIN + c4 * 4) * 2) ^ ((r & 7) << 4);     // T2 swizzle, 16B slots
        *reinterpret_cast<ushort4*>(AhiB + byte) = make_ushort4(h0, h1, h2, h3);
        *reinterpret_cast<ushort4*>(AloB + byte) = make_ushort4(l0, l1, l2, l3);
    }
    __syncthreads();

    // ---- gate GEMMs: wave wv owns cols [wv*64, wv*64+64) of BOTH Z and Ht; 32 rows ----
    f32x4 accZ[2][4], accH[2][4];
    #pragma unroll
    for (int m = 0; m < 2; ++m)
        #pragma unroll
        for (int nf = 0; nf < 4; ++nf) {
            accZ[m][nf] = (f32x4){0.f, 0.f, 0.f, 0.f};
            accH[m][nf] = (f32x4){0.f, 0.f, 0.f, 0.f};
        }

    bf16x8 ah[2], al[2];
    {   // A-frags for kb=0
        int koff = lk * 8;
        #pragma unroll
        for (int m = 0; m < 2; ++m) {
            int row = m * 16 + l16;
            int byte = ((row * CIN + koff) * 2) ^ ((row & 7) << 4);
            ah[m] = *reinterpret_cast<const bf16x8*>(AhiB + byte);
            al[m] = *reinterpret_cast<const bf16x8*>(AloB + byte);
        }
    }

    for (int kb = 0; kb < 8; ++kb) {
        #pragma unroll
        for (int nf = 0; nf < 4; ++nf) {
            // depth-1 prefetch of next (kb,nf) B-frags (tail clamps re-read kb=7, unused)
            int nnf = (nf + 1) & 3;
            int nkb = kb + (nf == 3 ? 1 : 0);
            int nkbc = nkb > 7 ? 7 : nkb;
            bf16x8 nZ = ldfrag(wf, (nfg0 + nnf)      * 8 + nkbc, lane);
            bf16x8 nH = ldfrag(wf, (16 + nfg0 + nnf) * 8 + nkbc, lane);
            // MFMAs on current frags: (xhi + xlo) * Whi
            #pragma unroll
            for (int m = 0; m < 2; ++m) {
                accZ[m][nf] = mfma16(ah[m], cZ, accZ[m][nf]);
                accZ[m][nf] = mfma16(al[m], cZ, accZ[m][nf]);
                accH[m][nf] = mfma16(ah[m], cH, accH[m][nf]);
                accH[m][nf] = mfma16(al[m], cH, accH[m][nf]);
            }
            if (nf == 3) {                     // A-frags for next kb (clamped at tail)
                int akb = kb < 7 ? kb + 1 : 7;
                int koff = akb * 32 + lk * 8;
                #pragma unroll
                for (int m = 0; m < 2; ++m) {
                    int row = m * 16 + l16;
                    int byte = ((row * CIN + koff) * 2) ^ ((row & 7) << 4);
                    ah[m] = *reinterpret_cast<const bf16x8*>(AhiB + byte);
                    al[m] = *reinterpret_cast<const bf16x8*>(AloB + byte);
                }
            }
            cZ = nZ; cH = nH;
        }
    }
    __syncthreads();   // all waves done reading x tiles before h overwrites smem

    // ---- nonlinearities + GRU blend; h -> LDS as (bf16 bits << 16) u32 words ----
    #pragma unroll
    for (int nf = 0; nf < 4; ++nf) {
        int col = wv * 64 + nf * 16 + l16;
        float bzv = bz[col], bhv = bh[col];
        #pragma unroll
        for (int m = 0; m < 2; ++m) {
            #pragma unroll
            for (int i = 0; i < 4; ++i) {
                float z  = 1.f / (1.f + __expf(-(accZ[m][nf][i] + bzv)));
                float t  = __expf(2.f * (accH[m][nf][i] + bhv));
                float th = (t - 1.f) / (t + 1.f);
                float H  = (1.f - z) * th;
                float h  = (H > 0.f) ? H : (__expf(H) - 1.f);   // elu(alpha=1)
                int row = m * 16 + lk * 4 + i;                  // C/D: row=(lane>>4)*4+reg
                unsigned pk = ((unsigned)f2bf(h)) << 16;        // h_hi bf16 in high halfword
                int byte = (row * 1024 + col * 4) ^ ((row & 7) << 4);  // u32 row stride 1 KB
                *reinterpret_cast<unsigned*>(smem + byte) = pk;
            }
        }
    }
    __syncthreads();

    // ---- out GEMM: wave wv owns out-cols [wv*16, wv*16+16), all 32 rows ----
    f32x4 accO[2];
    #pragma unroll
    for (int m = 0; m < 2; ++m) accO[m] = (f32x4){0.f, 0.f, 0.f, 0.f};

    bf16x8 cb = ldfrag(wf, 256 + wv * 8, lane);
    for (int kb = 0; kb < 8; ++kb) {
        int nk = kb < 7 ? kb + 1 : 7;
        bf16x8 nb = ldfrag(wf, 256 + wv * 8 + nk, lane);
        #pragma unroll
        for (int m = 0; m < 2; ++m) {
            int row = m * 16 + l16;
            int e0  = kb * 32 + lk * 8;
            int b0  = (row * 1024 + e0 * 4)      ^ ((row & 7) << 4);
            int b1  = (row * 1024 + e0 * 4 + 16) ^ ((row & 7) << 4);
            uint4 p0 = *reinterpret_cast<const uint4*>(smem + b0);
            uint4 p1 = *reinterpret_cast<const uint4*>(smem + b1);
            bf16x8 ha;
            ha[0] = (short)(p0.x >> 16); ha[1] = (short)(p0.y >> 16);
            ha[2] = (short)(p0.z >> 16); ha[3] = (short)(p0.w >> 16);
            ha[4] = (short)(p1.x >> 16); ha[5] = (short)(p1.y >> 16);
            ha[6] = (short)(p1.z >> 16); ha[7] = (short)(p1.w >> 16);
            accO[m] = mfma16(ha, cb, accO[m]);
        }
        cb = nb;
    }
    {
        int col = wv * 16 + l16;
        float bo = blin[col];
        #pragma unroll
        for (int m = 0; m < 2; ++m)
            #pragma unroll
            for (int i = 0; i < 4; ++i) {
                int row = row0 + m * 16 + lk * 4 + i;
                if (row < N_ROWS) out[(size_t)row * COUT + col] = accO[m][i] + bo;
            }
    }
}

// ---------------- fallback: round-2 f32 kernel (proven; used only if ws too small) ----------------
__global__ __launch_bounds__(256) void fallback_f32(
    const float* __restrict__ x, const float* __restrict__ mask,
    const float* __restrict__ wzr, const float* __restrict__ whr,
    const float* __restrict__ bz, const float* __restrict__ bh,
    const float* __restrict__ wlinr, const float* __restrict__ blin,
    float* __restrict__ out)
{
    __shared__ float xm[32][CIN];
    const int tid = threadIdx.x;
    const int row0 = blockIdx.x * 32;
    #pragma unroll
    for (int it = 0; it < 8; ++it) {
        int idx = it * 256 + tid;
        int r = idx >> 6, c4 = idx & 63, row = row0 + r;
        float4 v = make_float4(0.f, 0.f, 0.f, 0.f);
        if (row < N_ROWS) {
            float4 a = reinterpret_cast<const float4*>(x    + (size_t)row * CIN)[c4];
            float4 m = reinterpret_cast<const float4*>(mask + (size_t)row * CIN)[c4];
            v = make_float4(a.x * m.x, a.y * m.y, a.z * m.z, a.w * m.w);
        }
        reinterpret_cast<float4*>(&xm[r][0])[c4] = v;
    }
    __syncthreads();
    const int j0 = (tid & 63) * 4, r0 = (tid >> 6) * 8;
    float accz[4][8], acch[4][8];
    #pragma unroll
    for (int c = 0; c < 4; ++c)
        #pragma unroll
        for (int r = 0; r < 8; ++r) { accz[c][r] = 0.f; acch[c][r] = 0.f; }
    for (int k = 0; k < CIN; k += 4) {
        float4 wz4[4], wh4[4];
        #pragma unroll
        for (int kk = 0; kk < 4; ++kk) {
            float4 a0 = *reinterpret_cast<const float4*>(&wzr[(k + kk) * 256 + j0]);
            float4 a1 = *reinterpret_cast<const float4*>(&wzr[131072 + (k + kk) * 256 + j0]);
            wz4[kk] = make_float4(a0.x + a1.x, a0.y + a1.y, a0.z + a1.z, a0.w + a1.w);
            float4 b0 = *reinterpret_cast<const float4*>(&whr[(k + kk) * 256 + j0]);
            float4 b1 = *reinterpret_cast<const float4*>(&whr[131072 + (k + kk) * 256 + j0]);
            wh4[kk] = make_float4(b0.x + b1.x, b0.y + b1.y, b0.z + b1.z, b0.w + b1.w);
        }
        #pragma unroll
        for (int r = 0; r < 8; ++r) {
            float4 xv = *reinterpret_cast<const float4*>(&xm[r0 + r][k]);
            float xk[4] = {xv.x, xv.y, xv.z, xv.w};
            float wzc[4][4] = {{wz4[0].x,wz4[0].y,wz4[0].z,wz4[0].w},{wz4[1].x,wz4[1].y,wz4[1].z,wz4[1].w},
                               {wz4[2].x,wz4[2].y,wz4[2].z,wz4[2].w},{wz4[3].x,wz4[3].y,wz4[3].z,wz4[3].w}};
            float whc[4][4] = {{wh4[0].x,wh4[0].y,wh4[0].z,wh4[0].w},{wh4[1].x,wh4[1].y,wh4[1].z,wh4[1].w},
                               {wh4[2].x,wh4[2].y,wh4[2].z,wh4[2].w},{wh4[3].x,wh4[3].y,wh4[3].z,wh4[3].w}};
            #pragma unroll
            for (int kk = 0; kk < 4; ++kk)
                #pragma unroll
                for (int c = 0; c < 4; ++c) {
                    accz[c][r] = fmaf(xk[kk], wzc[kk][c], accz[c][r]);
                    acch[c][r] = fmaf(xk[kk], whc[kk][c], acch[c][r]);
                }
        }
    }
    float bzj[4], bhj[4];
    #pragma unroll
    for (int c = 0; c < 4; ++c) { bzj[c] = bz[j0 + c]; bhj[c] = bh[j0 + c]; }
    __syncthreads();
    #pragma unroll
    for (int r = 0; r < 8; ++r) {
        float hc[4];
        #pragma unroll
        for (int c = 0; c < 4; ++c) {
            float z  = 1.f / (1.f + expf(-(accz[c][r] + bzj[c])));
            float ht = tanhf(acch[c][r] + bhj[c]);
            float H  = (1.f - z) * ht;
            hc[c] = (H > 0.f) ? H : expm1f(H);
        }
        *reinterpret_cast<float4*>(&xm[r0 + r][j0]) = make_float4(hc[0], hc[1], hc[2], hc[3]);
    }
    __syncthreads();
    const int o = tid & 63;
    float acc[8];
    #pragma unroll
    for (int r = 0; r < 8; ++r) acc[r] = 0.f;
    for (int k = 0; k < CIN; k += 4) {
        float4 wv4 = *reinterpret_cast<const float4*>(&wlinr[o * 256 + k]);
        #pragma unroll
        for (int r = 0; r < 8; ++r) {
            float4 hv = *reinterpret_cast<const float4*>(&xm[r0 + r][k]);
            acc[r] = fmaf(hv.x, wv4.x, acc[r]);
            acc[r] = fmaf(hv.y, wv4.y, acc[r]);
            acc[r] = fmaf(hv.z, wv4.z, acc[r]);
            acc[r] = fmaf(hv.w, wv4.w, acc[r]);
        }
    }
    float bo = blin[o];
    #pragma unroll
    for (int r = 0; r < 8; ++r) {
        int row = row0 + r0 + r;
        if (row < N_ROWS) out[(size_t)row * COUT + o] = acc[r] + bo;
    }
}

extern "C" void kernel_launch(void* const* d_in, const int* in_sizes, int n_in,
                              void* d_out, int out_size, void* d_ws, size_t ws_size,
                              hipStream_t stream)
{
    const float* x    = (const float*)d_in[0];
    // d_in[1] edge_index, d_in[2] edge_weight: unused (K=1 identity term only)
    const float* mask = (const float*)d_in[3];
    const float* wz   = (const float*)d_in[4];
    const float* bz   = (const float*)d_in[5];
    // d_in[6] w_r, d_in[7] b_r: dead (H=0 -> reset gate unused)
    const float* wh   = (const float*)d_in[8];
    const float* bh   = (const float*)d_in[9];
    const float* wlin = (const float*)d_in[10];
    const float* blin = (const float*)d_in[11];
    float* outf = (float*)d_out;

    const size_t ws_need = 288 * 1024;   // 288 frags x 1 KB
    if (ws_size >= ws_need) {
        unsigned short* wsf = (unsigned short*)d_ws;
        prep_frags<<<72, 256, 0, stream>>>(wz, wh, wlin, wsf);
        dcrnn_mfma<<<(N_ROWS + BM - 1) / BM, 256, 0, stream>>>(
            x, mask, wsf, bz, bh, blin, outf);
    } else {
        fallback_f32<<<(N_ROWS + 31) / 32, 256, 0, stream>>>(
            x, mask, wz, wh, bz, bh, wlin, blin, outf);
    }
}

// Round 8
// 62.694 us; speedup vs baseline: 1.8677x; 1.0258x over previous
//
#include <hip/hip_runtime.h>
#include <hip/hip_bf16.h>

// DCRNN single-step, algebraically reduced (proven rounds 2-7):
//   xm = x * mask
//   Z  = sigmoid(xm @ WzE + bz),  WzE = w_z[0,0][:256] + w_z[1,0][:256]
//   Ht = tanh   (xm @ WhE + bh)
//   h  = elu((1 - Z) * Ht)         // H=0 -> Z*H drops; R/w_r/b_r dead; edges dead
//   out = h @ w_lin.T + b_lin      // f32 output
//
// Split-bf16 MFMA: x = xhi + xlo; W hi-only (R7-proven, absmax 0.0156 vs thr 0.0497).
// Round-8: latency attack via concurrency — 512-thread blocks (8 waves), each wave
// owns 2 nf slices (16 gate iters instead of 32); resident waves/CU ~9.3 -> ~16.
// Arithmetic and kb-accumulation order identical to R7 -> absmax unchanged.

typedef __attribute__((ext_vector_type(8))) short bf16x8;   // 8 bf16 = 4 VGPR
typedef __attribute__((ext_vector_type(4))) float f32x4;

constexpr int N_ROWS = 50000;
constexpr int CIN  = 256;
constexpr int COUT = 64;
constexpr int BM   = 32;

__device__ inline unsigned short f2bf(float f) {          // RNE f32 -> bf16 bits
    union { float f; unsigned u; } v; v.f = f;
    unsigned r = v.u + 0x7fffu + ((v.u >> 16) & 1u);
    return (unsigned short)(r >> 16);
}
__device__ inline float bf2f(unsigned short b) {
    union { unsigned u; float f; } v; v.u = ((unsigned)b) << 16;
    return v.f;
}
__device__ inline f32x4 mfma16(bf16x8 a, bf16x8 b, f32x4 c) {
    return __builtin_amdgcn_mfma_f32_16x16x32_bf16(a, b, c, 0, 0, 0);
}

// ---------------- weight prep: B-fragment-ordered bf16 (hi only; proven R7) ----------------
// Fragment f holds, for lane l, 8 bf16: B[k = kb*32 + (l>>4)*8 + j][n = nf*16 + (l&15)]
// gate frags f = (g*16 + nf)*8 + kb   g:0=Z,1=H   nf<16 kb<8   -> [0,256)
// out  frags f = 256 + nf*8 + kb      nf<4                     -> [256,288)
__global__ __launch_bounds__(256) void prep_frags(
    const float* __restrict__ wz, const float* __restrict__ wh,
    const float* __restrict__ wlin, unsigned short* __restrict__ ws)
{
    int t = blockIdx.x * 256 + threadIdx.x;
    int frag = t >> 6, lane = t & 63;
    if (frag >= 288) return;
    int g16 = lane & 15, kg = lane >> 4;
    unsigned short vals[8];
    if (frag < 256) {
        int kb = frag & 7, nf = (frag >> 3) & 15, g = frag >> 7;
        const float* wsrc = g ? wh : wz;
        int n = nf * 16 + g16;
        #pragma unroll
        for (int j = 0; j < 8; ++j) {
            int k = kb * 32 + kg * 8 + j;
            float v = wsrc[k * 256 + n] + wsrc[131072 + k * 256 + n];  // tap0 + tap1
            vals[j] = f2bf(v);
        }
    } else {
        int f = frag - 256;
        int kb = f & 7, nf = f >> 3;
        int n = nf * 16 + g16;                       // output column o
        #pragma unroll
        for (int j = 0; j < 8; ++j) {
            int k = kb * 32 + kg * 8 + j;
            vals[j] = f2bf(wlin[n * 256 + k]);       // B[k][o] = w_lin[o][k]
        }
    }
    unsigned short* dst = ws + (size_t)frag * 512 + lane * 8;
    #pragma unroll
    for (int j = 0; j < 8; ++j) dst[j] = vals[j];
}

__device__ inline bf16x8 ldfrag(const unsigned short* wf, int frag, int lane) {
    return *reinterpret_cast<const bf16x8*>(wf + (size_t)frag * 512 + lane * 8);
}

// ---------------- fused MFMA kernel (BM=32, 8 waves, 2 nf/wave) ----------------
__global__ __launch_bounds__(512, 4) void dcrnn_mfma(
    const float* __restrict__ x, const float* __restrict__ mask,
    const unsigned short* __restrict__ wf,
    const float* __restrict__ bz, const float* __restrict__ bh,
    const float* __restrict__ blin, float* __restrict__ out)
{
    __shared__ char smem[32768];               // phase A/B: Ahi|Alo bf16; phase C: h (bf16<<16) u32
    char* AhiB = smem;                         // 16 KB, XOR-swizzled bf16 x_hi (32x256)
    char* AloB = smem + 16384;                 // 16 KB, XOR-swizzled bf16 x_lo
    const int tid = threadIdx.x, lane = tid & 63, wv = tid >> 6;   // wv in [0,8)
    const int l16 = lane & 15, lk = lane >> 4;
    const int row0 = blockIdx.x * BM;
    const int nf0 = wv * 2;                    // this wave's 2 nf slices (cols wv*32..wv*32+32)

    // ---- issue first gate B-fragment loads before staging (overlap with HBM latency) ----
    bf16x8 rZ[2], rH[2];
    rZ[0] = ldfrag(wf, (nf0 + 0)      * 8, lane);
    rH[0] = ldfrag(wf, (16 + nf0 + 0) * 8, lane);
    rZ[1] = ldfrag(wf, (nf0 + 1)      * 8, lane);
    rH[1] = ldfrag(wf, (16 + nf0 + 1) * 8, lane);

    // ---- stage xm = x*mask -> hi/lo bf16 in LDS (f32x4 loads, swizzled 8B writes) ----
    #pragma unroll
    for (int it = 0; it < 4; ++it) {
        int f = it * 512 + tid;                // float4 slot in 32x256 tile
        int r = f >> 6, c4 = f & 63;
        int row = row0 + r;
        float4 xv = make_float4(0.f, 0.f, 0.f, 0.f), mv = xv;
        if (row < N_ROWS) {
            xv = reinterpret_cast<const float4*>(x    + (size_t)row * CIN)[c4];
            mv = reinterpret_cast<const float4*>(mask + (size_t)row * CIN)[c4];
        }
        float v0 = xv.x * mv.x, v1 = xv.y * mv.y, v2 = xv.z * mv.z, v3 = xv.w * mv.w;
        unsigned short h0 = f2bf(v0), h1 = f2bf(v1), h2 = f2bf(v2), h3 = f2bf(v3);
        unsigned short l0 = f2bf(v0 - bf2f(h0)), l1 = f2bf(v1 - bf2f(h1));
        unsigned short l2 = f2bf(v2 - bf2f(h2)), l3 = f2bf(v3 - bf2f(h3));
        int byte = ((r * CIN + c4 * 4) * 2) ^ ((r & 7) << 4);     // T2 swizzle, 16B slots
        *reinterpret_cast<ushort4*>(AhiB + byte) = make_ushort4(h0, h1, h2, h3);
        *reinterpret_cast<ushort4*>(AloB + byte) = make_ushort4(l0, l1, l2, l3);
    }
    __syncthreads();

    // ---- gate GEMMs: wave wv owns cols [wv*32, wv*32+32) of BOTH Z and Ht; 32 rows ----
    f32x4 accZ[2][2], accH[2][2];              // [nfi][m]
    #pragma unroll
    for (int nfi = 0; nfi < 2; ++nfi)
        #pragma unroll
        for (int m = 0; m < 2; ++m) {
            accZ[nfi][m] = (f32x4){0.f, 0.f, 0.f, 0.f};
            accH[nfi][m] = (f32x4){0.f, 0.f, 0.f, 0.f};
        }

    for (int kb = 0; kb < 8; ++kb) {
        bf16x8 ah[2], al[2];
        int koff = kb * 32 + lk * 8;
        #pragma unroll
        for (int m = 0; m < 2; ++m) {
            int row = m * 16 + l16;
            int byte = ((row * CIN + koff) * 2) ^ ((row & 7) << 4);
            ah[m] = *reinterpret_cast<const bf16x8*>(AhiB + byte);
            al[m] = *reinterpret_cast<const bf16x8*>(AloB + byte);
        }
        #pragma unroll
        for (int nfi = 0; nfi < 2; ++nfi) {
            // depth-2-iteration prefetch of next-kb B-frags (tail clamps, unused)
            int nkb = kb < 7 ? kb + 1 : 7;
            bf16x8 nZ = ldfrag(wf, (nf0 + nfi)      * 8 + nkb, lane);
            bf16x8 nH = ldfrag(wf, (16 + nf0 + nfi) * 8 + nkb, lane);
            // MFMAs on current frags: (xhi + xlo) * Whi   (same order as R7)
            #pragma unroll
            for (int m = 0; m < 2; ++m) {
                accZ[nfi][m] = mfma16(ah[m], rZ[nfi], accZ[nfi][m]);
                accZ[nfi][m] = mfma16(al[m], rZ[nfi], accZ[nfi][m]);
                accH[nfi][m] = mfma16(ah[m], rH[nfi], accH[nfi][m]);
                accH[nfi][m] = mfma16(al[m], rH[nfi], accH[nfi][m]);
            }
            rZ[nfi] = nZ; rH[nfi] = nH;
        }
    }

    // prefetch this wave's first out-GEMM B-frag (global; overlaps epilogue VALU)
    bf16x8 cb = ldfrag(wf, 256 + (wv & 3) * 8, lane);

    __syncthreads();   // all waves done reading x tiles before h overwrites smem

    // ---- nonlinearities + GRU blend; h -> LDS as (bf16 bits << 16) u32 words ----
    #pragma unroll
    for (int nfi = 0; nfi < 2; ++nfi) {
        int col = wv * 32 + nfi * 16 + l16;
        float bzv = bz[col], bhv = bh[col];
        #pragma unroll
        for (int m = 0; m < 2; ++m) {
            #pragma unroll
            for (int i = 0; i < 4; ++i) {
                float z  = 1.f / (1.f + __expf(-(accZ[nfi][m][i] + bzv)));
                float t  = __expf(2.f * (accH[nfi][m][i] + bhv));
                float th = (t - 1.f) / (t + 1.f);
                float H  = (1.f - z) * th;
                float h  = (H > 0.f) ? H : (__expf(H) - 1.f);   // elu(alpha=1)
                int row = m * 16 + lk * 4 + i;                  // C/D: row=(lane>>4)*4+reg
                unsigned pk = ((unsigned)f2bf(h)) << 16;        // h bf16 in high halfword
                int byte = (row * 1024 + col * 4) ^ ((row & 7) << 4);  // u32 row stride 1 KB
                *reinterpret_cast<unsigned*>(smem + byte) = pk;
            }
        }
    }
    __syncthreads();

    // ---- out GEMM: wave wv -> rows [(wv>>2)*16, +16), out-cols [(wv&3)*16, +16) ----
    f32x4 accO = (f32x4){0.f, 0.f, 0.f, 0.f};
    const int mo = wv >> 2;
    for (int kb = 0; kb < 8; ++kb) {
        int nk = kb < 7 ? kb + 1 : 7;
        bf16x8 nb = ldfrag(wf, 256 + (wv & 3) * 8 + nk, lane);
        int row = mo * 16 + l16;
        int e0  = kb * 32 + lk * 8;
        int b0  = (row * 1024 + e0 * 4)      ^ ((row & 7) << 4);
        int b1  = (row * 1024 + e0 * 4 + 16) ^ ((row & 7) << 4);
        uint4 p0 = *reinterpret_cast<const uint4*>(smem + b0);
        uint4 p1 = *reinterpret_cast<const uint4*>(smem + b1);
        bf16x8 ha;
        ha[0] = (short)(p0.x >> 16); ha[1] = (short)(p0.y >> 16);
        ha[2] = (short)(p0.z >> 16); ha[3] = (short)(p0.w >> 16);
        ha[4] = (short)(p1.x >> 16); ha[5] = (short)(p1.y >> 16);
        ha[6] = (short)(p1.z >> 16); ha[7] = (short)(p1.w >> 16);
        accO = mfma16(ha, cb, accO);
        cb = nb;
    }
    {
        int col = (wv & 3) * 16 + l16;
        float bo = blin[col];
        #pragma unroll
        for (int i = 0; i < 4; ++i) {
            int row = row0 + mo * 16 + lk * 4 + i;
            if (row < N_ROWS) out[(size_t)row * COUT + col] = accO[i] + bo;
        }
    }
}

// ---------------- fallback: round-2 f32 kernel (proven; used only if ws too small) ----------------
__global__ __launch_bounds__(256) void fallback_f32(
    const float* __restrict__ x, const float* __restrict__ mask,
    const float* __restrict__ wzr, const float* __restrict__ whr,
    const float* __restrict__ bz, const float* __restrict__ bh,
    const float* __restrict__ wlinr, const float* __restrict__ blin,
    float* __restrict__ out)
{
    __shared__ float xm[32][CIN];
    const int tid = threadIdx.x;
    const int row0 = blockIdx.x * 32;
    #pragma unroll
    for (int it = 0; it < 8; ++it) {
        int idx = it * 256 + tid;
        int r = idx >> 6, c4 = idx & 63, row = row0 + r;
        float4 v = make_float4(0.f, 0.f, 0.f, 0.f);
        if (row < N_ROWS) {
            float4 a = reinterpret_cast<const float4*>(x    + (size_t)row * CIN)[c4];
            float4 m = reinterpret_cast<const float4*>(mask + (size_t)row * CIN)[c4];
            v = make_float4(a.x * m.x, a.y * m.y, a.z * m.z, a.w * m.w);
        }
        reinterpret_cast<float4*>(&xm[r][0])[c4] = v;
    }
    __syncthreads();
    const int j0 = (tid & 63) * 4, r0 = (tid >> 6) * 8;
    float accz[4][8], acch[4][8];
    #pragma unroll
    for (int c = 0; c < 4; ++c)
        #pragma unroll
        for (int r = 0; r < 8; ++r) { accz[c][r] = 0.f; acch[c][r] = 0.f; }
    for (int k = 0; k < CIN; k += 4) {
        float4 wz4[4], wh4[4];
        #pragma unroll
        for (int kk = 0; kk < 4; ++kk) {
            float4 a0 = *reinterpret_cast<const float4*>(&wzr[(k + kk) * 256 + j0]);
            float4 a1 = *reinterpret_cast<const float4*>(&wzr[131072 + (k + kk) * 256 + j0]);
            wz4[kk] = make_float4(a0.x + a1.x, a0.y + a1.y, a0.z + a1.z, a0.w + a1.w);
            float4 b0 = *reinterpret_cast<const float4*>(&whr[(k + kk) * 256 + j0]);
            float4 b1 = *reinterpret_cast<const float4*>(&whr[131072 + (k + kk) * 256 + j0]);
            wh4[kk] = make_float4(b0.x + b1.x, b0.y + b1.y, b0.z + b1.z, b0.w + b1.w);
        }
        #pragma unroll
        for (int r = 0; r < 8; ++r) {
            float4 xv = *reinterpret_cast<const float4*>(&xm[r0 + r][k]);
            float xk[4] = {xv.x, xv.y, xv.z, xv.w};
            float wzc[4][4] = {{wz4[0].x,wz4[0].y,wz4[0].z,wz4[0].w},{wz4[1].x,wz4[1].y,wz4[1].z,wz4[1].w},
                               {wz4[2].x,wz4[2].y,wz4[2].z,wz4[2].w},{wz4[3].x,wz4[3].y,wz4[3].z,wz4[3].w}};
            float whc[4][4] = {{wh4[0].x,wh4[0].y,wh4[0].z,wh4[0].w},{wh4[1].x,wh4[1].y,wh4[1].z,wh4[1].w},
                               {wh4[2].x,wh4[2].y,wh4[2].z,wh4[2].w},{wh4[3].x,wh4[3].y,wh4[3].z,wh4[3].w}};
            #pragma unroll
            for (int kk = 0; kk < 4; ++kk)
                #pragma unroll
                for (int c = 0; c < 4; ++c) {
                    accz[c][r] = fmaf(xk[kk], wzc[kk][c], accz[c][r]);
                    acch[c][r] = fmaf(xk[kk], whc[kk][c], acch[c][r]);
                }
        }
    }
    float bzj[4], bhj[4];
    #pragma unroll
    for (int c = 0; c < 4; ++c) { bzj[c] = bz[j0 + c]; bhj[c] = bh[j0 + c]; }
    __syncthreads();
    #pragma unroll
    for (int r = 0; r < 8; ++r) {
        float hc[4];
        #pragma unroll
        for (int c = 0; c < 4; ++c) {
            float z  = 1.f / (1.f + expf(-(accz[c][r] + bzj[c])));
            float ht = tanhf(acch[c][r] + bhj[c]);
            float H  = (1.f - z) * ht;
            hc[c] = (H > 0.f) ? H : expm1f(H);
        }
        *reinterpret_cast<float4*>(&xm[r0 + r][j0]) = make_float4(hc[0], hc[1], hc[2], hc[3]);
    }
    __syncthreads();
    const int o = tid & 63;
    float acc[8];
    #pragma unroll
    for (int r = 0; r < 8; ++r) acc[r] = 0.f;
    for (int k = 0; k < CIN; k += 4) {
        float4 wv4 = *reinterpret_cast<const float4*>(&wlinr[o * 256 + k]);
        #pragma unroll
        for (int r = 0; r < 8; ++r) {
            float4 hv = *reinterpret_cast<const float4*>(&xm[r0 + r][k]);
            acc[r] = fmaf(hv.x, wv4.x, acc[r]);
            acc[r] = fmaf(hv.y, wv4.y, acc[r]);
            acc[r] = fmaf(hv.z, wv4.z, acc[r]);
            acc[r] = fmaf(hv.w, wv4.w, acc[r]);
        }
    }
    float bo = blin[o];
    #pragma unroll
    for (int r = 0; r < 8; ++r) {
        int row = row0 + r0 + r;
        if (row < N_ROWS) out[(size_t)row * COUT + o] = acc[r] + bo;
    }
}

extern "C" void kernel_launch(void* const* d_in, const int* in_sizes, int n_in,
                              void* d_out, int out_size, void* d_ws, size_t ws_size,
                              hipStream_t stream)
{
    const float* x    = (const float*)d_in[0];
    // d_in[1] edge_index, d_in[2] edge_weight: unused (K=1 identity term only)
    const float* mask = (const float*)d_in[3];
    const float* wz   = (const float*)d_in[4];
    const float* bz   = (const float*)d_in[5];
    // d_in[6] w_r, d_in[7] b_r: dead (H=0 -> reset gate unused)
    const float* wh   = (const float*)d_in[8];
    const float* bh   = (const float*)d_in[9];
    const float* wlin = (const float*)d_in[10];
    const float* blin = (const float*)d_in[11];
    float* outf = (float*)d_out;

    const size_t ws_need = 288 * 1024;   // 288 frags x 1 KB
    if (ws_size >= ws_need) {
        unsigned short* wsf = (unsigned short*)d_ws;
        prep_frags<<<72, 256, 0, stream>>>(wz, wh, wlin, wsf);
        dcrnn_mfma<<<(N_ROWS + BM - 1) / BM, 512, 0, stream>>>(
            x, mask, wsf, bz, bh, blin, outf);
    } else {
        fallback_f32<<<(N_ROWS + 31) / 32, 256, 0, stream>>>(
            x, mask, wz, wh, bz, bh, wlin, blin, outf);
    }
}